// Round 1
// baseline (1245.092 us; speedup 1.0000x reference)
//
#include <hip/hip_runtime.h>
#include <math.h>

// Attention pooling: context[b,d] = sum_t softmax_t( V . tanh(full[b,t,:]@W1 + last[b,:]@W2 + b1+b2) ) * full[b,t,d]
// B=32 T=2048 D=512 U=512, fp32.
// bV is softmax-invariant -> dropped. b1+b2 folded into h2.
// ws layout: scores/p [B*T] floats @0, h2 [B*U] floats @B*T*4. Total 320 KB.

#define BB 32
#define TT 2048
#define DD 512
#define UU 512

// ---------------- kernel 1: h2[b,u] = last[b,:].W2[:,u] + b1[u] + b2[u] ----------------
__global__ __launch_bounds__(256) void h2_kernel(const float* __restrict__ last,
                                                 const float* __restrict__ W2,
                                                 const float* __restrict__ b1,
                                                 const float* __restrict__ b2,
                                                 float* __restrict__ h2) {
    __shared__ float ls[DD];
    const int b = blockIdx.x;
    const int tid = threadIdx.x;
    for (int i = tid; i < DD; i += 256) ls[i] = last[b * DD + i];
    __syncthreads();
    for (int u = tid; u < UU; u += 256) {
        float acc = 0.f;
#pragma unroll 8
        for (int d = 0; d < DD; ++d) acc += ls[d] * W2[d * UU + u];
        h2[b * UU + u] = acc + b1[u] + b2[u];
    }
}

// ---------------- kernel 2: scores[b,t] = V . tanh(full[b,t,:]@W1 + h2[b,:]) ----------------
// Block: 32 t-rows of one batch, full U=512. 256 threads = 16 ty (t pairs) x 16 tx (u pairs).
// Thread (ty,tx): t in {t0+ty, t0+ty+16}; u in {32*j + 2*tx + e : j<16, e<2}.
__global__ __launch_bounds__(256) void score_kernel(const float* __restrict__ full,
                                                    const float* __restrict__ W1,
                                                    const float* __restrict__ h2,
                                                    const float* __restrict__ V,
                                                    float* __restrict__ scores) {
    __shared__ float a_tile[32][36];    // [t][d], pad 36: rows hit distinct banks, 16B aligned
    __shared__ float b_tile[32][UU];    // [d][u]
    __shared__ float h2s[UU];
    __shared__ float Vs[UU];

    const int bid = blockIdx.x;
    const int b  = bid >> 6;            // 64 blocks per batch
    const int t0 = (bid & 63) << 5;
    const int tid = threadIdx.x;
    const int tx = tid & 15;
    const int ty = tid >> 4;

    for (int i = tid; i < UU; i += 256) { h2s[i] = h2[b * UU + i]; Vs[i] = V[i]; }

    float acc[2][32];
#pragma unroll
    for (int i = 0; i < 2; ++i)
#pragma unroll
        for (int j = 0; j < 32; ++j) acc[i][j] = 0.f;

    const int ar = tid >> 3;            // a-tile row 0..31
    const int ac = (tid & 7) << 2;      // a-tile col 0,4,..,28

    for (int d0 = 0; d0 < DD; d0 += 32) {
        // stage A: full[b, t0..t0+31, d0..d0+31]
        {
            const float4 v = *(const float4*)&full[((size_t)(b * TT + t0 + ar)) * DD + d0 + ac];
            *(float4*)&a_tile[ar][ac] = v;
        }
        // stage B: W1[d0..d0+31, 0..511]  (4096 float4, 16 per thread, coalesced)
        for (int k = tid; k < (32 * UU) / 4; k += 256) {
            const int r = k >> 7;
            const int c = (k & 127) << 2;
            *(float4*)&b_tile[r][c] = *(const float4*)&W1[(size_t)(d0 + r) * UU + c];
        }
        __syncthreads();

#pragma unroll 8
        for (int d = 0; d < 32; ++d) {
            const float a0 = a_tile[ty][d];
            const float a1 = a_tile[ty + 16][d];
#pragma unroll
            for (int j = 0; j < 16; ++j) {
                const float2 w = *(const float2*)&b_tile[d][32 * j + 2 * tx];
                acc[0][2 * j]     += a0 * w.x;
                acc[0][2 * j + 1] += a0 * w.y;
                acc[1][2 * j]     += a1 * w.x;
                acc[1][2 * j + 1] += a1 * w.y;
            }
        }
        __syncthreads();
    }

    // epilogue: tanh + dot with V, reduce over u
    float s[2] = {0.f, 0.f};
#pragma unroll
    for (int i = 0; i < 2; ++i) {
#pragma unroll
        for (int j = 0; j < 16; ++j) {
#pragma unroll
            for (int e = 0; e < 2; ++e) {
                const int u = 32 * j + 2 * tx + e;
                const float h = acc[i][2 * j + e] + h2s[u];
                s[i] += tanhf(h) * Vs[u];
            }
        }
    }
    // reduce across tx (low 4 lane bits)
#pragma unroll
    for (int off = 1; off < 16; off <<= 1) {
        s[0] += __shfl_xor(s[0], off, 64);
        s[1] += __shfl_xor(s[1], off, 64);
    }
    if (tx == 0) {
        scores[b * TT + t0 + ty]      = s[0];
        scores[b * TT + t0 + ty + 16] = s[1];
    }
}

// ---------------- kernel 3a: softmax over T per batch; normalize in place; zero out ----------------
__global__ __launch_bounds__(256) void softmax_kernel(float* __restrict__ scores,
                                                      float* __restrict__ out) {
    const int b = blockIdx.x;
    const int tid = threadIdx.x;
    __shared__ float red[256];

    out[b * DD + tid] = 0.f;
    out[b * DD + 256 + tid] = 0.f;

    float local[8];
    float m = -1e30f;
#pragma unroll
    for (int i = 0; i < 8; ++i) {
        local[i] = scores[b * TT + i * 256 + tid];
        m = fmaxf(m, local[i]);
    }
    red[tid] = m;
    __syncthreads();
    for (int s = 128; s > 0; s >>= 1) {
        if (tid < s) red[tid] = fmaxf(red[tid], red[tid + s]);
        __syncthreads();
    }
    const float mx = red[0];
    __syncthreads();

    float sum = 0.f;
#pragma unroll
    for (int i = 0; i < 8; ++i) {
        local[i] = expf(local[i] - mx);
        sum += local[i];
    }
    red[tid] = sum;
    __syncthreads();
    for (int s = 128; s > 0; s >>= 1) {
        if (tid < s) red[tid] += red[tid + s];
        __syncthreads();
    }
    const float inv = 1.f / red[0];
#pragma unroll
    for (int i = 0; i < 8; ++i) scores[b * TT + i * 256 + tid] = local[i] * inv;
}

// ---------------- kernel 3b: context[b,d] += sum_t p[b,t]*full[b,t,d] (t-chunks of 256) ----------------
__global__ __launch_bounds__(256) void context_kernel(const float* __restrict__ full,
                                                      const float* __restrict__ p,
                                                      float* __restrict__ out) {
    const int bid = blockIdx.x;
    const int b  = bid >> 3;
    const int t0 = (bid & 7) << 8;
    const int tid = threadIdx.x;
    __shared__ float ps[256];
    ps[tid] = p[b * TT + t0 + tid];
    __syncthreads();

    float acc0 = 0.f, acc1 = 0.f;
    const float* base = full + ((size_t)(b * TT + t0)) * DD;
#pragma unroll 4
    for (int t = 0; t < 256; ++t) {
        const float w = ps[t];
        acc0 += w * base[(size_t)t * DD + tid];
        acc1 += w * base[(size_t)t * DD + tid + 256];
    }
    atomicAdd(&out[b * DD + tid], acc0);
    atomicAdd(&out[b * DD + tid + 256], acc1);
}

extern "C" void kernel_launch(void* const* d_in, const int* in_sizes, int n_in,
                              void* d_out, int out_size, void* d_ws, size_t ws_size,
                              hipStream_t stream) {
    const float* full = (const float*)d_in[0];
    const float* last = (const float*)d_in[1];
    const float* W1   = (const float*)d_in[2];
    const float* b1   = (const float*)d_in[3];
    const float* W2   = (const float*)d_in[4];
    const float* b2   = (const float*)d_in[5];
    const float* V    = (const float*)d_in[6];
    // d_in[7] = bV: softmax-invariant, unused.

    float* out    = (float*)d_out;
    float* scores = (float*)d_ws;                    // B*T floats
    float* h2     = (float*)d_ws + (size_t)BB * TT;  // B*U floats

    h2_kernel<<<BB, 256, 0, stream>>>(last, W2, b1, b2, h2);
    score_kernel<<<BB * (TT / 32), 256, 0, stream>>>(full, W1, h2, V, scores);
    softmax_kernel<<<BB, 256, 0, stream>>>(scores, out);
    context_kernel<<<BB * (TT / 256), 256, 0, stream>>>(full, scores, out);
}

// Round 2
// 362.059 us; speedup vs baseline: 3.4389x; 3.4389x over previous
//
#include <hip/hip_runtime.h>
#include <math.h>

// Attention pooling: context[b,d] = sum_t softmax_t( V . tanh(full[b,t,:]@W1 + last[b,:]@W2 + b1+b2) ) * full[b,t,d]
// B=32 T=2048 D=512 U=512, fp32 in/out. bV softmax-invariant -> dropped; b1+b2 folded into h2.
// R2: score GEMM moved to bf16 MFMA (16x16x32), fp32 accumulate. absmax headroom 20x permits bf16.
// ws layout (floats): scores [B*T] @0, h2 [B*U] @B*T, then W1T [U*D] bf16 (shorts).

#define BB 32
#define TT 2048
#define DD 512
#define UU 512

typedef short bf16x8 __attribute__((ext_vector_type(8)));
typedef short bf16x4 __attribute__((ext_vector_type(4)));
typedef float f32x4  __attribute__((ext_vector_type(4)));

static __device__ __forceinline__ short f2bf(float f) {
    unsigned x = __float_as_uint(f);
    unsigned r = (x + 0x7fffu + ((x >> 16) & 1u)) >> 16;   // RNE
    return (short)r;
}

static __device__ __forceinline__ float fast_tanh(float x) {
    // tanh(x) = 1 - 2/(e^{2x}+1); robust at +-inf. v_exp + v_rcp, ~1e-6 rel err.
    float e = __expf(2.f * x);
    return 1.f - 2.f * __builtin_amdgcn_rcpf(e + 1.f);
}

// ---------------- kernel 0: W1T[u][d] = bf16(W1[d][u]) ----------------
__global__ __launch_bounds__(256) void w1t_kernel(const float* __restrict__ W1,
                                                  short* __restrict__ W1T) {
    const int u = blockIdx.x;
    const int tid = threadIdx.x;
    W1T[u * DD + tid]       = f2bf(W1[(size_t)tid * UU + u]);
    W1T[u * DD + 256 + tid] = f2bf(W1[(size_t)(tid + 256) * UU + u]);
}

// ---------------- kernel 1: h2[b,u] = last[b,:].W2[:,u] + b1[u] + b2[u] (fp32) ----------------
__global__ __launch_bounds__(256) void h2_kernel(const float* __restrict__ last,
                                                 const float* __restrict__ W2,
                                                 const float* __restrict__ b1,
                                                 const float* __restrict__ b2,
                                                 float* __restrict__ h2) {
    __shared__ float ls[DD];
    const int b = blockIdx.x;
    const int tid = threadIdx.x;
    for (int i = tid; i < DD; i += 256) ls[i] = last[b * DD + i];
    __syncthreads();
    for (int u = tid; u < UU; u += 256) {
        float acc = 0.f;
#pragma unroll 8
        for (int d = 0; d < DD; ++d) acc += ls[d] * W2[d * UU + u];
        h2[b * UU + u] = acc + b1[u] + b2[u];
    }
}

// ---------------- kernel 2: scores[b,t] = V . tanh(full[b,t,:]@W1 + h2[b,:]) — bf16 MFMA ----------------
// Block: 32 t-rows x full U=512, K=512. 4 waves; wave w covers u in [w*128,(w+1)*128).
// MFMA 16x16x32: A lane layout A[m=lane&15][k=quad*8+j]; B[k=quad*8+j][n=lane&15];
// C/D: col=lane&15, row=quad*4+reg.
__global__ __launch_bounds__(256) void score_kernel(const float* __restrict__ full,
                                                    const short* __restrict__ W1T,
                                                    const float* __restrict__ h2,
                                                    const float* __restrict__ V,
                                                    float* __restrict__ scores) {
    __shared__ __align__(16) short a_lds[32 * 40];   // [t][k] bf16, row stride 40
    __shared__ __align__(16) short b_lds[512 * 40];  // [u][k] bf16, row stride 40
    __shared__ float h2s[UU];
    __shared__ float Vs[UU];
    __shared__ float score_red[32];

    const int bid = blockIdx.x;
    const int b  = bid >> 6;            // 64 blocks per batch
    const int t0 = (bid & 63) << 5;
    const int tid = threadIdx.x;
    const int w    = tid >> 6;
    const int lane = tid & 63;
    const int quad = lane >> 4;
    const int col  = lane & 15;

    for (int i = tid; i < UU; i += 256) { h2s[i] = h2[b * UU + i]; Vs[i] = V[i]; }
    if (tid < 32) score_red[tid] = 0.f;

    f32x4 acc[2][8];
#pragma unroll
    for (int i = 0; i < 2; ++i)
#pragma unroll
        for (int j = 0; j < 8; ++j) acc[i][j] = (f32x4){0.f, 0.f, 0.f, 0.f};

    const int arow = tid >> 3;          // 0..31
    const int acol = (tid & 7) << 2;    // 0,4,..,28

    for (int k0 = 0; k0 < DD; k0 += 32) {
        // stage A: full[b, t0..t0+31, k0..k0+31] fp32 -> bf16
        {
            const float4 v = *(const float4*)&full[((size_t)(b * TT + t0 + arow)) * DD + k0 + acol];
            bf16x4 s = {f2bf(v.x), f2bf(v.y), f2bf(v.z), f2bf(v.w)};
            *(bf16x4*)&a_lds[arow * 40 + acol] = s;
        }
        // stage B: W1T[u][k0..k0+31], 512 u-rows x 32 k (bf16), 16B chunks
#pragma unroll
        for (int i = 0; i < 8; ++i) {
            const int id = tid + 256 * i;
            const int u = id >> 2;
            const int c = id & 3;
            *(bf16x8*)&b_lds[u * 40 + c * 8] = *(const bf16x8*)&W1T[u * DD + k0 + c * 8];
        }
        __syncthreads();

        const bf16x8 af0 = *(const bf16x8*)&a_lds[col * 40 + quad * 8];
        const bf16x8 af1 = *(const bf16x8*)&a_lds[(col + 16) * 40 + quad * 8];
#pragma unroll
        for (int nt = 0; nt < 8; ++nt) {
            const bf16x8 bf = *(const bf16x8*)&b_lds[(w * 128 + nt * 16 + col) * 40 + quad * 8];
            acc[0][nt] = __builtin_amdgcn_mfma_f32_16x16x32_bf16(af0, bf, acc[0][nt], 0, 0, 0);
            acc[1][nt] = __builtin_amdgcn_mfma_f32_16x16x32_bf16(af1, bf, acc[1][nt], 0, 0, 0);
        }
        __syncthreads();
    }

    // epilogue: tanh + dot with V, reduce over u
    float srow[8];
#pragma unroll
    for (int i = 0; i < 8; ++i) srow[i] = 0.f;
#pragma unroll
    for (int mt = 0; mt < 2; ++mt) {
#pragma unroll
        for (int nt = 0; nt < 8; ++nt) {
            const int u = w * 128 + nt * 16 + col;
            const float hv = h2s[u];
            const float vv = Vs[u];
#pragma unroll
            for (int r = 0; r < 4; ++r) {
                srow[mt * 4 + r] += fast_tanh(acc[mt][nt][r] + hv) * vv;
            }
        }
    }
    // reduce across the 16 lanes of each quad
#pragma unroll
    for (int off = 1; off < 16; off <<= 1) {
#pragma unroll
        for (int i = 0; i < 8; ++i) srow[i] += __shfl_xor(srow[i], off, 64);
    }
    if (col == 0) {
#pragma unroll
        for (int mt = 0; mt < 2; ++mt)
#pragma unroll
            for (int r = 0; r < 4; ++r)
                atomicAdd(&score_red[mt * 16 + quad * 4 + r], srow[mt * 4 + r]);
    }
    __syncthreads();
    if (tid < 32) scores[b * TT + t0 + tid] = score_red[tid];
}

// ---------------- kernel 3a: softmax over T per batch; normalize in place; zero out ----------------
__global__ __launch_bounds__(256) void softmax_kernel(float* __restrict__ scores,
                                                      float* __restrict__ out) {
    const int b = blockIdx.x;
    const int tid = threadIdx.x;
    __shared__ float red[256];

    out[b * DD + tid] = 0.f;
    out[b * DD + 256 + tid] = 0.f;

    float local[8];
    float m = -1e30f;
#pragma unroll
    for (int i = 0; i < 8; ++i) {
        local[i] = scores[b * TT + i * 256 + tid];
        m = fmaxf(m, local[i]);
    }
    red[tid] = m;
    __syncthreads();
    for (int s = 128; s > 0; s >>= 1) {
        if (tid < s) red[tid] = fmaxf(red[tid], red[tid + s]);
        __syncthreads();
    }
    const float mx = red[0];
    __syncthreads();

    float sum = 0.f;
#pragma unroll
    for (int i = 0; i < 8; ++i) {
        local[i] = __expf(local[i] - mx);
        sum += local[i];
    }
    red[tid] = sum;
    __syncthreads();
    for (int s = 128; s > 0; s >>= 1) {
        if (tid < s) red[tid] += red[tid + s];
        __syncthreads();
    }
    const float inv = 1.f / red[0];
#pragma unroll
    for (int i = 0; i < 8; ++i) scores[b * TT + i * 256 + tid] = local[i] * inv;
}

// ---------------- kernel 3b: context[b,d] += sum_t p[b,t]*full[b,t,d] (t-chunks of 128) ----------------
__global__ __launch_bounds__(256) void context_kernel(const float* __restrict__ full,
                                                      const float* __restrict__ p,
                                                      float* __restrict__ out) {
    const int bid = blockIdx.x;
    const int b  = bid >> 4;
    const int t0 = (bid & 15) << 7;
    const int tid = threadIdx.x;
    __shared__ float ps[128];
    if (tid < 128) ps[tid] = p[b * TT + t0 + tid];
    __syncthreads();

    float acc0 = 0.f, acc1 = 0.f;
    const float* base = full + ((size_t)(b * TT + t0)) * DD;
#pragma unroll 4
    for (int t = 0; t < 128; ++t) {
        const float w = ps[t];
        acc0 += w * base[(size_t)t * DD + tid];
        acc1 += w * base[(size_t)t * DD + tid + 256];
    }
    atomicAdd(&out[b * DD + tid], acc0);
    atomicAdd(&out[b * DD + tid + 256], acc1);
}

extern "C" void kernel_launch(void* const* d_in, const int* in_sizes, int n_in,
                              void* d_out, int out_size, void* d_ws, size_t ws_size,
                              hipStream_t stream) {
    const float* full = (const float*)d_in[0];
    const float* last = (const float*)d_in[1];
    const float* W1   = (const float*)d_in[2];
    const float* b1   = (const float*)d_in[3];
    const float* W2   = (const float*)d_in[4];
    const float* b2   = (const float*)d_in[5];
    const float* V    = (const float*)d_in[6];
    // d_in[7] = bV: softmax-invariant, unused.

    float* out    = (float*)d_out;
    float* scores = (float*)d_ws;                          // B*T floats
    float* h2     = (float*)d_ws + (size_t)BB * TT;        // B*U floats
    short* W1T    = (short*)(h2 + (size_t)BB * UU);        // U*D bf16

    w1t_kernel<<<UU, 256, 0, stream>>>(W1, W1T);
    h2_kernel<<<BB, 256, 0, stream>>>(last, W2, b1, b2, h2);
    score_kernel<<<BB * (TT / 32), 256, 0, stream>>>(full, W1T, h2, V, scores);
    softmax_kernel<<<BB, 256, 0, stream>>>(scores, out);
    context_kernel<<<BB * (TT / 128), 256, 0, stream>>>(full, scores, out);
}

// Round 3
// 302.308 us; speedup vs baseline: 4.1186x; 1.1976x over previous
//
#include <hip/hip_runtime.h>
#include <math.h>

// Attention pooling: context[b,d] = sum_t softmax_t( V . tanh(full[b,t,:]@W1 + last[b,:]@W2 + b1+b2) ) * full[b,t,d]
// B=32 T=2048 D=512 U=512, fp32 in/out. bV softmax-invariant -> dropped; b1+b2 folded into h2.
// R3: score M=64/block, B-tile staged via global_load_lds(16) with XOR-swizzled chunk slots;
//     prep = fused {W1 transpose->bf16, h2}; context = float4 loads.
// ws (floats): scores [B*T] @0, h2 [B*U] @B*T, then W1T [U*D] bf16 (shorts).

#define BB 32
#define TT 2048
#define DD 512
#define UU 512

typedef short bf16x8 __attribute__((ext_vector_type(8)));
typedef short bf16x4 __attribute__((ext_vector_type(4)));
typedef float f32x4  __attribute__((ext_vector_type(4)));

static __device__ __forceinline__ short f2bf(float f) {
    unsigned x = __float_as_uint(f);
    return (short)((x + 0x7fffu + ((x >> 16) & 1u)) >> 16);   // RNE
}

static __device__ __forceinline__ float fast_tanh(float x) {
    // tanh(x) = 1 - 2/(e^{2x}+1); robust at +-inf.
    float e = __expf(2.f * x);
    return 1.f - 2.f * __builtin_amdgcn_rcpf(e + 1.f);
}

// ---------------- prep: blocks [0,256): W1T[u][d]=bf16(W1[d][u]) tile-transposed; [256,288): h2 ----------------
__global__ __launch_bounds__(256) void prep_kernel(const float* __restrict__ W1,
                                                   short* __restrict__ W1T,
                                                   const float* __restrict__ last,
                                                   const float* __restrict__ W2,
                                                   const float* __restrict__ b1,
                                                   const float* __restrict__ b2,
                                                   float* __restrict__ h2) {
    __shared__ float tile[32][33];
    __shared__ float ls[DD];
    const int bid = blockIdx.x;
    const int tid = threadIdx.x;
    if (bid < 256) {
        const int tr = (bid >> 4) << 5;   // d-block origin
        const int tc = (bid & 15) << 5;   // u-block origin
#pragma unroll
        for (int p = 0; p < 4; ++p) {
            const int r = p * 8 + (tid >> 5), c = tid & 31;
            tile[r][c] = W1[(size_t)(tr + r) * UU + tc + c];   // coalesced read
        }
        __syncthreads();
#pragma unroll
        for (int p = 0; p < 4; ++p) {
            const int r = p * 8 + (tid >> 5), c = tid & 31;    // r=u-local, c=d-local
            W1T[(size_t)(tc + r) * DD + tr + c] = f2bf(tile[c][r]);  // coalesced write
        }
    } else {
        const int b = bid - 256;
        for (int i = tid; i < DD; i += 256) ls[i] = last[b * DD + i];
        __syncthreads();
        float a0 = 0.f, a1 = 0.f;
#pragma unroll 8
        for (int d = 0; d < DD; ++d) {
            const float l = ls[d];
            a0 += l * W2[d * UU + tid];
            a1 += l * W2[d * UU + tid + 256];
        }
        h2[b * UU + tid]       = a0 + b1[tid] + b2[tid];
        h2[b * UU + tid + 256] = a1 + b1[tid + 256] + b2[tid + 256];
    }
}

// ---------------- score: scores[b,t] = V . tanh(full[b,t,:]@W1 + h2[b,:]) — bf16 MFMA, M=64 ----------------
// 1024 blocks: b = bid>>5, t0 = (bid&31)*64. 4 waves; wave w owns u in [w*128,(w+1)*128).
// Per K-step(32): wave = 4 m-frags x 8 n-frags = 32 MFMA 16x16x32.
// b_lds layout: 16B chunk slots; logical (u, c=k-octet) lives at slot u*4 + (c ^ (u&3));
// DMA lane i (id = chunkbase+i) fetches global (u=id>>2, c=(id&3)^(u&3)) so slot id holds it.
__global__ __launch_bounds__(256, 2) void score_kernel(const float* __restrict__ full,
                                                       const short* __restrict__ W1T,
                                                       const float* __restrict__ h2,
                                                       const float* __restrict__ V,
                                                       float* __restrict__ scores) {
    __shared__ __align__(16) short a_lds[64 * 40];    // [t][k] bf16, row stride 40
    __shared__ __align__(16) short b_lds[512 * 32];   // chunk-slot layout (no pad: DMA target)
    __shared__ float h2s[UU];
    __shared__ float Vs[UU];
    __shared__ float score_red[64];

    const int bid = blockIdx.x;
    const int b  = bid >> 5;
    const int t0 = (bid & 31) << 6;
    const int tid = threadIdx.x;
    const int w    = tid >> 6;
    const int lane = tid & 63;
    const int quad = lane >> 4;
    const int col  = lane & 15;

    for (int i = tid; i < UU; i += 256) { h2s[i] = h2[b * UU + i]; Vs[i] = V[i]; }
    if (tid < 64) score_red[tid] = 0.f;

    f32x4 acc[4][8];
#pragma unroll
    for (int i = 0; i < 4; ++i)
#pragma unroll
        for (int j = 0; j < 8; ++j) acc[i][j] = (f32x4){0.f, 0.f, 0.f, 0.f};

    const int arow = tid >> 3;          // 0..31 (second pass +32)
    const int ac   = (tid & 7) << 2;    // k-col 0,4,..,28

    for (int k0 = 0; k0 < DD; k0 += 32) {
        // A: full[b, t0..t0+63, k0..k0+31] fp32 -> bf16, coalesced float4 reads
#pragma unroll
        for (int i = 0; i < 2; ++i) {
            const int row = arow + 32 * i;
            const float4 v = *(const float4*)&full[((size_t)(b * TT + t0 + row)) * DD + k0 + ac];
            bf16x4 s = {f2bf(v.x), f2bf(v.y), f2bf(v.z), f2bf(v.w)};
            *(bf16x4*)&a_lds[row * 40 + ac] = s;
        }
        // B: 2048 16B-chunks via direct-to-LDS DMA, 8 issues per wave
#pragma unroll
        for (int i = 0; i < 8; ++i) {
            const int id = (w * 8 + i) * 64 + lane;
            const int u  = id >> 2;
            const int c  = (id & 3) ^ (u & 3);
            const short* g = W1T + (size_t)u * DD + k0 + c * 8;
            __builtin_amdgcn_global_load_lds(
                (const __attribute__((address_space(1))) void*)g,
                (__attribute__((address_space(3))) void*)&b_lds[(w * 8 + i) * 64 * 8],
                16, 0, 0);
        }
        __syncthreads();

        bf16x8 af[4];
#pragma unroll
        for (int mt = 0; mt < 4; ++mt)
            af[mt] = *(const bf16x8*)&a_lds[(mt * 16 + col) * 40 + quad * 8];
#pragma unroll
        for (int nt = 0; nt < 8; ++nt) {
            const int u = w * 128 + nt * 16 + col;
            const bf16x8 bf = *(const bf16x8*)&b_lds[(u * 4 + (quad ^ (u & 3))) * 8];
#pragma unroll
            for (int mt = 0; mt < 4; ++mt)
                acc[mt][nt] = __builtin_amdgcn_mfma_f32_16x16x32_bf16(af[mt], bf, acc[mt][nt], 0, 0, 0);
        }
        __syncthreads();
    }

    // epilogue: tanh + dot with V over this wave's u-slice; rows = mt*16 + quad*4 + r
    float srow[16];
#pragma unroll
    for (int i = 0; i < 16; ++i) srow[i] = 0.f;
#pragma unroll
    for (int mt = 0; mt < 4; ++mt) {
#pragma unroll
        for (int nt = 0; nt < 8; ++nt) {
            const int u = w * 128 + nt * 16 + col;
            const float hv = h2s[u];
            const float vv = Vs[u];
#pragma unroll
            for (int r = 0; r < 4; ++r)
                srow[mt * 4 + r] += fast_tanh(acc[mt][nt][r] + hv) * vv;
        }
    }
#pragma unroll
    for (int off = 1; off < 16; off <<= 1) {
#pragma unroll
        for (int i = 0; i < 16; ++i) srow[i] += __shfl_xor(srow[i], off, 64);
    }
    if (col == 0) {
#pragma unroll
        for (int mt = 0; mt < 4; ++mt)
#pragma unroll
            for (int r = 0; r < 4; ++r)
                atomicAdd(&score_red[mt * 16 + quad * 4 + r], srow[mt * 4 + r]);
    }
    __syncthreads();
    if (tid < 64) scores[b * TT + t0 + tid] = score_red[tid];
}

// ---------------- softmax over T per batch; normalize in place; zero out ----------------
__global__ __launch_bounds__(256) void softmax_kernel(float* __restrict__ scores,
                                                      float* __restrict__ out) {
    const int b = blockIdx.x;
    const int tid = threadIdx.x;
    __shared__ float red[256];

    out[b * DD + tid] = 0.f;
    out[b * DD + 256 + tid] = 0.f;

    float local[8];
    float m = -1e30f;
#pragma unroll
    for (int i = 0; i < 8; ++i) {
        local[i] = scores[b * TT + i * 256 + tid];
        m = fmaxf(m, local[i]);
    }
    red[tid] = m;
    __syncthreads();
    for (int s = 128; s > 0; s >>= 1) {
        if (tid < s) red[tid] = fmaxf(red[tid], red[tid + s]);
        __syncthreads();
    }
    const float mx = red[0];
    __syncthreads();

    float sum = 0.f;
#pragma unroll
    for (int i = 0; i < 8; ++i) {
        local[i] = __expf(local[i] - mx);
        sum += local[i];
    }
    red[tid] = sum;
    __syncthreads();
    for (int s = 128; s > 0; s >>= 1) {
        if (tid < s) red[tid] += red[tid + s];
        __syncthreads();
    }
    const float inv = 1.f / red[0];
#pragma unroll
    for (int i = 0; i < 8; ++i) scores[b * TT + i * 256 + tid] = local[i] * inv;
}

// ---------------- context[b,d] += sum_t p[b,t]*full[b,t,d], t-chunks of 64, float4 loads ----------------
__global__ __launch_bounds__(256) void context_kernel(const float* __restrict__ full,
                                                      const float* __restrict__ p,
                                                      float* __restrict__ out) {
    const int bid = blockIdx.x;
    const int b  = bid >> 5;
    const int t0 = (bid & 31) << 6;
    const int tid = threadIdx.x;
    const int q   = tid & 127;          // d-quad index (d = 4q..4q+3)
    const int par = tid >> 7;           // t parity
    __shared__ float ps[64];
    __shared__ float4 red[128];
    if (tid < 64) ps[tid] = p[b * TT + t0 + tid];
    __syncthreads();

    float ax = 0.f, ay = 0.f, az = 0.f, aw = 0.f;
    const float* base = full + ((size_t)(b * TT + t0)) * DD;
#pragma unroll 4
    for (int it = 0; it < 32; ++it) {
        const int tl = it * 2 + par;
        const float4 v = *(const float4*)&base[(size_t)tl * DD + q * 4];
        const float wg = ps[tl];
        ax += wg * v.x; ay += wg * v.y; az += wg * v.z; aw += wg * v.w;
    }
    if (par == 1) red[q] = make_float4(ax, ay, az, aw);
    __syncthreads();
    if (par == 0) {
        const float4 o = red[q];
        atomicAdd(&out[b * DD + q * 4 + 0], ax + o.x);
        atomicAdd(&out[b * DD + q * 4 + 1], ay + o.y);
        atomicAdd(&out[b * DD + q * 4 + 2], az + o.z);
        atomicAdd(&out[b * DD + q * 4 + 3], aw + o.w);
    }
}

extern "C" void kernel_launch(void* const* d_in, const int* in_sizes, int n_in,
                              void* d_out, int out_size, void* d_ws, size_t ws_size,
                              hipStream_t stream) {
    const float* full = (const float*)d_in[0];
    const float* last = (const float*)d_in[1];
    const float* W1   = (const float*)d_in[2];
    const float* b1   = (const float*)d_in[3];
    const float* W2   = (const float*)d_in[4];
    const float* b2   = (const float*)d_in[5];
    const float* V    = (const float*)d_in[6];
    // d_in[7] = bV: softmax-invariant, unused.

    float* out    = (float*)d_out;
    float* scores = (float*)d_ws;                          // B*T floats
    float* h2     = (float*)d_ws + (size_t)BB * TT;        // B*U floats
    short* W1T    = (short*)(h2 + (size_t)BB * UU);        // U*D bf16

    prep_kernel<<<256 + BB, 256, 0, stream>>>(W1, W1T, last, W2, b1, b2, h2);
    score_kernel<<<BB * (TT / 64), 256, 0, stream>>>(full, W1T, h2, V, scores);
    softmax_kernel<<<BB, 256, 0, stream>>>(scores, out);
    context_kernel<<<BB * (TT / 64), 256, 0, stream>>>(full, scores, out);
}